// Round 1
// baseline (1949.677 us; speedup 1.0000x reference)
//
#include <hip/hip_runtime.h>
#include <hip/hip_bf16.h>

// FastKANLayer as one bf16 MFMA GEMM: out[b,j] = A[b,k] @ Wb[k,j], k = i*36+c.
//   c<35: A = cubic B-spline basis (4-tap sparse), Wb = spline_weight[i,j,c]
//   c==35: A = silu(clip(x)),                      Wb = base_scale[i,j]
// M=4096, N=1024, K=36864.
// R6 (this round):
//  - T2 LDS swizzle BAKED INTO the A2/W2 memory image: each 64B row's four
//    16B chunks stored at chunk ^ ((row>>1)&3). global_load_lds stays linear
//    (rule 21), gemm reads at koS = (quad ^ ((lm>>1)&3))*8. Kills the
//    measured 2.83e7 SQ_LDS_BANK_CONFLICT (13% of gemm cycles).
//  - BM=256 x BN=512, NSPLIT=8 (grid still 256 = 1 block/CU): A2 (302 MB)
//    read 2x instead of 4x -> tile traffic 2.42 -> 1.81 GB. LDS 144 KB.
//  - prep_w + prep_a2 fused into one launch, 1:4 interleaved block decode,
//    so the read-heavy W path overlaps the write-heavy A2 path. prep_w slab
//    loads vectorized float4, LDS halved to 36 KB (q-phases sequential).
// R5 carried: triple-buffered K-loop, counted vmcnt (never 0 mid-loop),
// single barrier/step. R2 lesson: no __launch_bounds__ min-waves (spills acc).

#define IN_DIM 1024
#define OUT_DIM 1024
#define NC 35
#define KPI 36
#define KTOT (IN_DIM * KPI)      // 36864
#define NW (KTOT / 32)           // 1152 k-windows of 32
#define MROWS 4096
#define BM 256
#define BN 512
#define BK 32
#define NSPLIT 8
#define WPC (NW / NSPLIT)        // 144 windows per kc chunk

typedef __attribute__((ext_vector_type(8))) __bf16 bf16x8;
typedef __attribute__((ext_vector_type(4))) float f32x4;

__device__ __forceinline__ unsigned short f2bf(float f) {
  unsigned int u = __builtin_bit_cast(unsigned int, f);
  u = (u + 0x7FFFu + ((u >> 16) & 1u)) >> 16;   // RNE
  return (unsigned short)u;
}

__device__ __forceinline__ uint4 pack8(const unsigned short* v) {
  uint4 t4;
  t4.x = (unsigned)v[0] | ((unsigned)v[1] << 16);
  t4.y = (unsigned)v[2] | ((unsigned)v[3] << 16);
  t4.z = (unsigned)v[4] | ((unsigned)v[5] << 16);
  t4.w = (unsigned)v[6] | ((unsigned)v[7] << 16);
  return t4;
}

// ---- fused prep: W2[w][n][32] (75.5 MB) + A2[w][b][32] (302 MB), both as
// swizzled LDS tile images. Block decode interleaves 1 W-block : 4 A-blocks
// in dispatch order so the two memory-direction profiles overlap.
__global__ __launch_bounds__(256) void prep_fused(const float* __restrict__ x,
                                                  const float* __restrict__ sw,
                                                  const float* __restrict__ bs,
                                                  unsigned short* __restrict__ w2,
                                                  unsigned short* __restrict__ a2) {
  __shared__ __align__(16) float sbuf[256 * NC];   // 35.8 KB (W-part only)
  const int tid = threadIdx.x;
  const int id = blockIdx.x;
  const int r5 = id % 5;
  const int q5 = id / 5;
  const int swz = (tid >> 1) & 3;                  // row-bits 1:2 -> chunk XOR

  if (r5 == 0) {
    // ---- W-part: q5 in [0, 4608): w = q5 % NW, n-slab = q5 / NW.
    const int w = q5 % NW;
    const int n0 = (q5 / NW) * 256;
    const int k0 = w * 32;
    const int i0 = k0 / KPI;
    const int off0 = k0 - i0 * KPI;                // in {0,4,...,32}
    int split = KPI - off0;
    if (split > 32) split = 32;
    unsigned short v[32];
    {  // phase 0: slab i0 (covers kk < split; includes the c==35 silu slot)
      const float4* s4 = (const float4*)(sw + ((size_t)i0 * OUT_DIM + n0) * NC);
      float4* d4 = (float4*)sbuf;
      for (int t = tid; t < 256 * NC / 4; t += 256) d4[t] = s4[t];
      float bsv = bs[(size_t)i0 * OUT_DIM + n0 + tid];
      __syncthreads();
#pragma unroll
      for (int kk = 0; kk < 32; ++kk)
        if (kk < split) {
          int c = off0 + kk;                       // 0..35
          float f = (c < NC) ? sbuf[tid * NC + c] : bsv;
          v[kk] = f2bf(f);
        }
    }
    if (split < 32) {  // phase 1: slab i0+1 (c = kk - split, always < NC)
      __syncthreads();
      const float4* s4 =
          (const float4*)(sw + ((size_t)(i0 + 1) * OUT_DIM + n0) * NC);
      float4* d4 = (float4*)sbuf;
      for (int t = tid; t < 256 * NC / 4; t += 256) d4[t] = s4[t];
      __syncthreads();
#pragma unroll
      for (int kk = 0; kk < 32; ++kk)
        if (kk >= split) v[kk] = f2bf(sbuf[tid * NC + (kk - split)]);
    }
    uint4* dst = (uint4*)(w2 + ((size_t)w * OUT_DIM + n0 + tid) * 32);
#pragma unroll
    for (int j = 0; j < 4; ++j) dst[j ^ swz] = pack8(&v[8 * j]);
  } else {
    // ---- A-part: qa in [0, 18432): w = qa % NW, b-slab = qa / NW.
    const int qa = q5 * 4 + (r5 - 1);
    const int w = qa % NW;
    const int b = (qa / NW) * 256 + tid;
    const int k0 = w * 32;
    const int i0 = k0 / KPI;
    const int i1 = (k0 + 31) / KPI;                // i0 or i0+1
    const int iq[2] = {i0, i1};
    int si[2];
    float tv0[2], tv1[2], tv2[2], tv3[2], sg[2];
#pragma unroll
    for (int q = 0; q < 2; ++q) {
      float xv = x[(size_t)b * IN_DIM + iq[q]];    // column read; L2-served
      float xn = fminf(fmaxf(xv, -0.99f), 0.99f);
      float u = (xn + 1.0f) * 17.0f;               // 1/h = 17
      float sf = floorf(u);
      si[q] = (int)sf;
      float f = u - sf, g = 1.0f - f;
      float f2 = f * f, g2 = g * g;
      tv0[q] = g2 * g * (1.f / 6.f);
      tv1[q] = 0.66666667f - f2 + 0.5f * f2 * f;
      tv2[q] = 0.66666667f - g2 + 0.5f * g2 * g;
      tv3[q] = f2 * f * (1.f / 6.f);
      sg[q] = xn / (1.0f + __expf(-xn));
    }
    unsigned short v[32];
#pragma unroll
    for (int kk = 0; kk < 32; ++kk) {
      int k = k0 + kk;
      int q = (k >= (i0 + 1) * KPI) ? 1 : 0;
      int c = k - iq[q] * KPI;
      float val;
      if (c == NC) {
        val = sg[q];
      } else {
        int rel = c - (si[q] - 1);
        val = (rel == 0) ? tv0[q]
            : (rel == 1) ? tv1[q]
            : (rel == 2) ? tv2[q]
            : (rel == 3) ? tv3[q] : 0.0f;
      }
      v[kk] = f2bf(val);
    }
    uint4* dst = (uint4*)(a2 + ((size_t)w * MROWS + b) * 32);
#pragma unroll
    for (int j = 0; j < 4; ++j) dst[j ^ swz] = pack8(&v[8 * j]);
  }
}

// ---- fast GEMM: 256x512 tile, 8 waves (2m x 4n, 128x128 each), triple-
// buffered async K-loop, counted vmcnt(6), swizzled ds_read addressing.
__global__ __launch_bounds__(512) void kan_gemm4(const unsigned short* __restrict__ A2,
                                                 const unsigned short* __restrict__ W2,
                                                 float* __restrict__ out) {
  __shared__ __align__(16) unsigned short As[3][BM * BK];   // 3 x 16 KB
  __shared__ __align__(16) unsigned short Ws[3][BN * BK];   // 3 x 32 KB

  const int tid = threadIdx.x;
  const int mt = blockIdx.x, nt = blockIdx.y, kc = blockIdx.z;

  const int lane = tid & 63;
  const int wid = tid >> 6;                      // 0..7
  const int wm = (wid & 1) * 128;                // 2 m-wave rows
  const int wn = (wid >> 1) * 128;               // 4 n-wave cols
  const int lm = lane & 15;
  const int quad = lane >> 4;
  const int koS = (quad ^ ((lm >> 1) & 3)) * 8;  // swizzled chunk address

  f32x4 acc[8][8];
#pragma unroll
  for (int a = 0; a < 8; ++a)
#pragma unroll
    for (int b = 0; b < 8; ++b) acc[a][b] = f32x4{0.f, 0.f, 0.f, 0.f};

  // staging: A tile = 16 x 1KB chunks (2/wave), W tile = 32 x 1KB (4/wave).
  const unsigned short* Abase = A2 + (size_t)(mt * BM) * 32 + lane * 8;
  const unsigned short* Wbase = W2 + (size_t)(nt * BN) * 32 + lane * 8;

  auto issue = [&](int buf, int w) {
    const size_t aoff = (size_t)w * (MROWS * 32);
    const size_t woff = (size_t)w * (OUT_DIM * 32);
#pragma unroll
    for (int c = 0; c < 2; ++c) {
      const int g = wid * 2 + c;
      __builtin_amdgcn_global_load_lds(
          (const __attribute__((address_space(1))) unsigned int*)(Abase + aoff + (size_t)g * 512),
          (__attribute__((address_space(3))) unsigned int*)(&As[buf][g * 512]),
          16, 0, 0);
    }
#pragma unroll
    for (int c = 0; c < 4; ++c) {
      const int g = wid * 4 + c;
      __builtin_amdgcn_global_load_lds(
          (const __attribute__((address_space(1))) unsigned int*)(Wbase + woff + (size_t)g * 512),
          (__attribute__((address_space(3))) unsigned int*)(&Ws[buf][g * 512]),
          16, 0, 0);
    }
  };

  issue(0, kc * WPC);
  int cur = 0, nxt = 1;
  for (int step = 0; step < WPC; ++step) {
    if (step + 1 < WPC) {
      issue(nxt, kc * WPC + step + 1);
      // wait this step's 6 loads only; prefetch (newest 6) stays in flight
      asm volatile("s_waitcnt vmcnt(6) lgkmcnt(0)\ns_barrier" ::: "memory");
    } else {
      asm volatile("s_waitcnt vmcnt(0) lgkmcnt(0)\ns_barrier" ::: "memory");
    }

    uint4 af[8];
#pragma unroll
    for (int mi = 0; mi < 8; ++mi)
      af[mi] = *(const uint4*)(&As[cur][(wm + mi * 16 + lm) * BK + koS]);
#pragma unroll
    for (int h = 0; h < 2; ++h) {
      uint4 bfr[4];
#pragma unroll
      for (int nj = 0; nj < 4; ++nj)
        bfr[nj] = *(const uint4*)(&Ws[cur][(wn + h * 64 + nj * 16 + lm) * BK + koS]);
#pragma unroll
      for (int mi = 0; mi < 8; ++mi)
#pragma unroll
        for (int nj = 0; nj < 4; ++nj)
          acc[mi][h * 4 + nj] = __builtin_amdgcn_mfma_f32_16x16x32_bf16(
              __builtin_bit_cast(bf16x8, af[mi]), __builtin_bit_cast(bf16x8, bfr[nj]),
              acc[mi][h * 4 + nj], 0, 0, 0);
    }

    cur = nxt;
    nxt = (nxt == 2) ? 0 : nxt + 1;
  }

  // epilogue: C/D layout col=lane&15 (n), row=quad*4+reg (m); split-K atomics.
  // ni*16 == (ni>>2)*64 + (ni&3)*16 so acc[mi][ni] -> col wn + ni*16.
#pragma unroll
  for (int mi = 0; mi < 8; ++mi)
#pragma unroll
    for (int ni = 0; ni < 8; ++ni)
#pragma unroll
      for (int r = 0; r < 4; ++r) {
        int row = mt * BM + wm + mi * 16 + quad * 4 + r;
        int col = nt * BN + wn + ni * 16 + lm;
        atomicAdd(&out[(size_t)row * OUT_DIM + col], acc[mi][ni][r]);
      }
}

// ================= fallback path (R1-proven), used only if ws too small ====
#define FB_BM 128
#define FB_BN 128
#define FB_BKPA 40
#define FB_KCH 9216
#define FB_NSTEP 288

__global__ __launch_bounds__(256) void prep_wb_fb(const float* __restrict__ sw,
                                                  const float* __restrict__ bs,
                                                  unsigned short* __restrict__ wb) {
  int id = blockIdx.x * 256 + threadIdx.x;
  int i = id & (IN_DIM - 1);
  int n = id >> 10;
  const float* s = sw + (size_t)i * (OUT_DIM * NC) + (size_t)n * NC;
  unsigned short v[KPI];
#pragma unroll
  for (int c = 0; c < NC; ++c) v[c] = f2bf(s[c]);
  v[NC] = f2bf(bs[(size_t)i * OUT_DIM + n]);
  uint2* dst = (uint2*)(wb + (size_t)n * KTOT + (size_t)i * KPI);
#pragma unroll
  for (int w = 0; w < 9; ++w) {
    uint2 t;
    t.x = (unsigned)v[4 * w + 0] | ((unsigned)v[4 * w + 1] << 16);
    t.y = (unsigned)v[4 * w + 2] | ((unsigned)v[4 * w + 3] << 16);
    dst[w] = t;
  }
}

template <bool USE_WB>
__global__ __launch_bounds__(256) void kan_gemm_fb(const float* __restrict__ x,
                                                   const unsigned short* __restrict__ wb,
                                                   const float* __restrict__ sw,
                                                   const float* __restrict__ bs,
                                                   float* __restrict__ out) {
  __shared__ __align__(16) unsigned short As[FB_BM * FB_BKPA];
  __shared__ __align__(16) unsigned short Wsm[FB_BN * FB_BKPA];

  const int tid = threadIdx.x;
  const int mt = blockIdx.x, nt = blockIdx.y, kc = blockIdx.z;
  const int sb = tid & 127;
  const int shalf = tid >> 7;
  const int klo = shalf * 16;
  const int wrow = tid >> 1;
  const int whal = tid & 1;
  const int lane = tid & 63;
  const int wid = tid >> 6;
  const int wm = (wid & 1) * 64;
  const int wn = (wid >> 1) * 64;
  const int lm = lane & 15;
  const int quad = lane >> 4;
  const int ko = quad * 8;

  f32x4 acc[4][4];
#pragma unroll
  for (int a = 0; a < 4; ++a)
#pragma unroll
    for (int b = 0; b < 4; ++b) acc[a][b] = f32x4{0.f, 0.f, 0.f, 0.f};

  const float* xrow = x + (size_t)(mt * FB_BM + sb) * IN_DIM;

  for (int step = 0; step < FB_NSTEP; ++step) {
    const int kbase = kc * FB_KCH + step * BK;
    {
      uint4 z = make_uint4(0, 0, 0, 0);
      uint4* az = (uint4*)(&As[sb * FB_BKPA + klo]);
      az[0] = z;
      az[1] = z;
    }
    {
      const int ilo = kbase / KPI;
      const int ihi = (kbase + BK - 1) / KPI;
      for (int ii = ilo; ii <= ihi; ++ii) {
        float xv = xrow[ii];
        float xn = fminf(fmaxf(xv, -0.99f), 0.99f);
        float u = (xn + 1.0f) * 17.0f;
        float sf = floorf(u);
        int s = (int)sf;
        float f = u - sf, g = 1.0f - f;
        float f2 = f * f, g2 = g * g;
        float v0 = g2 * g * (1.f / 6.f);
        float v1 = 0.66666667f - f2 + 0.5f * f2 * f;
        float v2 = 0.66666667f - g2 + 0.5f * g2 * g;
        float v3 = f2 * f * (1.f / 6.f);
        float sig = xn / (1.0f + __expf(-xn));
        const int kb0 = ii * KPI - kbase;
#pragma unroll
        for (int t = 0; t < 4; ++t) {
          int c = s - 1 + t;
          float v = (t == 0) ? v0 : (t == 1) ? v1 : (t == 2) ? v2 : v3;
          int kq = kb0 + c;
          if (c >= 0 && c < NC && kq >= klo && kq < klo + 16)
            As[sb * FB_BKPA + kq] = f2bf(v);
        }
        int kqb = kb0 + NC;
        if (kqb >= klo && kqb < klo + 16) As[sb * FB_BKPA + kqb] = f2bf(sig);
      }
    }
    if (USE_WB) {
      const unsigned short* src = wb + (size_t)(nt * FB_BN + wrow) * KTOT + kbase + whal * 16;
      uint4 w0 = ((const uint4*)src)[0];
      uint4 w1 = ((const uint4*)src)[1];
      uint4* wd = (uint4*)(&Wsm[wrow * FB_BKPA + whal * 16]);
      wd[0] = w0;
      wd[1] = w1;
    } else {
      const int j = nt * FB_BN + wrow;
      unsigned int p[8];
#pragma unroll
      for (int q = 0; q < 8; ++q) {
        unsigned int lohi = 0;
#pragma unroll
        for (int h = 0; h < 2; ++h) {
          int k = kbase + whal * 16 + q * 2 + h;
          int i = k / KPI;
          int c = k - i * KPI;
          float v = (c < NC) ? sw[(size_t)i * (OUT_DIM * NC) + (size_t)j * NC + c]
                             : bs[(size_t)i * OUT_DIM + j];
          lohi |= ((unsigned int)f2bf(v)) << (16 * h);
        }
        p[q] = lohi;
      }
      uint4* wd = (uint4*)(&Wsm[wrow * FB_BKPA + whal * 16]);
      wd[0] = make_uint4(p[0], p[1], p[2], p[3]);
      wd[1] = make_uint4(p[4], p[5], p[6], p[7]);
    }

    __syncthreads();

    uint4 af[4], bfr[4];
#pragma unroll
    for (int mi = 0; mi < 4; ++mi)
      af[mi] = *(const uint4*)(&As[(wm + mi * 16 + lm) * FB_BKPA + ko]);
#pragma unroll
    for (int ni = 0; ni < 4; ++ni)
      bfr[ni] = *(const uint4*)(&Wsm[(wn + ni * 16 + lm) * FB_BKPA + ko]);
#pragma unroll
    for (int mi = 0; mi < 4; ++mi)
#pragma unroll
      for (int ni = 0; ni < 4; ++ni)
        acc[mi][ni] = __builtin_amdgcn_mfma_f32_16x16x32_bf16(
            __builtin_bit_cast(bf16x8, af[mi]), __builtin_bit_cast(bf16x8, bfr[ni]),
            acc[mi][ni], 0, 0, 0);

    __syncthreads();
  }

#pragma unroll
  for (int mi = 0; mi < 4; ++mi)
#pragma unroll
    for (int ni = 0; ni < 4; ++ni)
#pragma unroll
      for (int r = 0; r < 4; ++r) {
        int row = mt * FB_BM + wm + mi * 16 + quad * 4 + r;
        int col = nt * FB_BN + wn + ni * 16 + lm;
        atomicAdd(&out[(size_t)row * OUT_DIM + col], acc[mi][ni][r]);
      }
}

extern "C" void kernel_launch(void* const* d_in, const int* in_sizes, int n_in,
                              void* d_out, int out_size, void* d_ws, size_t ws_size,
                              hipStream_t stream) {
  const float* x = (const float*)d_in[0];
  const float* sw = (const float*)d_in[1];
  const float* bs = (const float*)d_in[2];
  float* out = (float*)d_out;

  hipMemsetAsync(d_out, 0, (size_t)MROWS * OUT_DIM * sizeof(float), stream);

  const size_t WB_BYTES = (size_t)NW * OUT_DIM * 32 * sizeof(unsigned short);  // 75.5 MB
  const size_t A_BYTES = (size_t)NW * MROWS * 32 * sizeof(unsigned short);     // 302 MB

  if (ws_size >= WB_BYTES + A_BYTES) {
    unsigned short* w2 = (unsigned short*)d_ws;
    unsigned short* a2 = (unsigned short*)((char*)d_ws + WB_BYTES);
    // 4608 W-blocks + 18432 A-blocks, interleaved 1:4 in dispatch order.
    prep_fused<<<dim3(5 * NW * 4), 256, 0, stream>>>(x, sw, bs, w2, a2);
    kan_gemm4<<<dim3(MROWS / BM, OUT_DIM / BN, NSPLIT), 512, 0, stream>>>(a2, w2, out);
  } else if (ws_size >= WB_BYTES) {
    unsigned short* wbp = (unsigned short*)d_ws;
    prep_wb_fb<<<(IN_DIM * OUT_DIM) / 256, 256, 0, stream>>>(sw, bs, wbp);
    kan_gemm_fb<true><<<dim3(32, 8, 4), 256, 0, stream>>>(x, wbp, sw, bs, out);
  } else {
    kan_gemm_fb<false><<<dim3(32, 8, 4), 256, 0, stream>>>(x, nullptr, sw, bs, out);
  }
}

// Round 3
// 707.845 us; speedup vs baseline: 2.7544x; 2.7544x over previous
//
#include <hip/hip_runtime.h>
#include <hip/hip_bf16.h>

// FastKANLayer as one bf16 MFMA GEMM: out[b,j] = A[b,k] @ Wb[k,j], k = i*36+c.
//   c<35: A = cubic B-spline basis (4-tap sparse), Wb = spline_weight[i,j,c]
//   c==35: A = silu(clip(x)),                      Wb = base_scale[i,j]
// M=4096, N=1024, K=36864.
// R8 = R7 resubmitted verbatim (R7 bench died to a container infra failure;
// source re-audited: no OOB, no hang path, gemm is R5-proven + R6-proven
// swizzle only).
// R7:
//  - GEMM reverted to the R5-proven geometry (BM=BN=256, NSPLIT=4, triple
//    buffer, vmcnt(4), acc[4][8]) -- R6's BN=512/NSPLIT=8 caused a 4 GB
//    atomic-write storm (WRITE_SIZE 65MB->3.98GB) and 4.5x slowdown.
//    Single delta kept from R6: the baked chunk-XOR LDS swizzle
//    (verified: SQ_LDS_BANK_CONFLICT 2.83e7 -> 0, bit-identical output).
//  - prep_a2 rewritten: k-group decomposition (8 i's / 9 windows per block),
//    x read ROW-wise float4 (each element once: ~600MB column-gather -> 32MB),
//    bf16 conversion once per i, fully static slot assembly.
//  - prep_w rewritten: direct per-thread reads (one load per slot, ~150MB
//    instead of 282MB full-slab staging), no LDS, no barriers.

#define IN_DIM 1024
#define OUT_DIM 1024
#define NC 35
#define KPI 36
#define KTOT (IN_DIM * KPI)      // 36864
#define NW (KTOT / 32)           // 1152 k-windows of 32
#define MROWS 4096
#define BM 256
#define BN 256
#define BK 32
#define NSPLIT 4
#define WPC (NW / NSPLIT)        // 288 windows per kc chunk

typedef __attribute__((ext_vector_type(8))) __bf16 bf16x8;
typedef __attribute__((ext_vector_type(4))) float f32x4;

__device__ __forceinline__ unsigned short f2bf(float f) {
  unsigned int u = __builtin_bit_cast(unsigned int, f);
  u = (u + 0x7FFFu + ((u >> 16) & 1u)) >> 16;   // RNE
  return (unsigned short)u;
}

__device__ __forceinline__ uint4 pack8(const unsigned short* v) {
  uint4 t4;
  t4.x = (unsigned)v[0] | ((unsigned)v[1] << 16);
  t4.y = (unsigned)v[2] | ((unsigned)v[3] << 16);
  t4.z = (unsigned)v[4] | ((unsigned)v[5] << 16);
  t4.w = (unsigned)v[6] | ((unsigned)v[7] << 16);
  return t4;
}

// ---- prep: W2[w][n][32] bf16 (75.5 MB), swizzled LDS tile image. ----
// One load per k-slot via select-computed address; each sw element read ~once.
__global__ __launch_bounds__(256) void prep_w2(const float* __restrict__ sw,
                                               const float* __restrict__ bs,
                                               unsigned short* __restrict__ w2) {
  const int tid = threadIdx.x;
  const int w = blockIdx.x;
  const int n = blockIdx.y * 256 + tid;
  const int k0 = w * 32;
  const int i0 = k0 / KPI;
  const int off0 = k0 - i0 * KPI;                 // in {0,4,...,32}
  const int split = (KPI - off0 < 32) ? (KPI - off0) : 32;
  const int i1 = (i0 + 1 < IN_DIM) ? (i0 + 1) : i0;   // clamp (unused if split==32)
  const float* p0 = sw + ((size_t)i0 * OUT_DIM + n) * NC;
  const float* p1 = sw + ((size_t)i1 * OUT_DIM + n) * NC;
  const float bsv = bs[(size_t)i0 * OUT_DIM + n];
  const int swz = (tid >> 1) & 3;                 // row bits 1:2 -> chunk XOR

  unsigned short v[32];
#pragma unroll
  for (int kk = 0; kk < 32; ++kk) {
    const int c = off0 + kk;                      // wave-uniform
    const bool ph0 = (kk < split);
    const float* base = ph0 ? p0 : p1;
    const int idx = ph0 ? (c < NC ? c : 0) : (kk - split);  // clamped: no OOB
    float fv = base[idx];
    if (ph0 && c == NC) fv = bsv;                 // silu-weight slot
    v[kk] = f2bf(fv);
  }
  uint4* dst = (uint4*)(w2 + ((size_t)w * OUT_DIM + n) * 32);
#pragma unroll
  for (int j = 0; j < 4; ++j) dst[j ^ swz] = pack8(&v[8 * j]);
}

// ---- prep: A2[w][b][32] bf16 basis (302 MB), swizzled LDS tile image. ----
// Block = (k-group g: i in [8g,8g+8), w in [9g,9g+9)) x (256-row b-slab).
// x read row-wise (2x float4/thread, each element once chip-wide); slot->(i,c)
// mapping is compile-time; bf16 conversion once per i.
__global__ __launch_bounds__(256) void prep_a2t(const float* __restrict__ x,
                                                unsigned short* __restrict__ a2) {
  const int tid = threadIdx.x;
  const int g = blockIdx.x;                       // 0..127
  const int b = blockIdx.y * 256 + tid;
  const int i0 = g * 8;
  const int w0 = g * 9;
  const int swz = (tid >> 1) & 3;

  float4 xa = *(const float4*)(x + (size_t)b * IN_DIM + i0);
  float4 xb = *(const float4*)(x + (size_t)b * IN_DIM + i0 + 4);
  const float xv[8] = {xa.x, xa.y, xa.z, xa.w, xb.x, xb.y, xb.z, xb.w};

  int si[8];
  unsigned short tb0[8], tb1[8], tb2[8], tb3[8], sgb[8];
#pragma unroll
  for (int q = 0; q < 8; ++q) {
    float xn = fminf(fmaxf(xv[q], -0.99f), 0.99f);
    float u = (xn + 1.0f) * 17.0f;                // 1/h = 17
    float sf = floorf(u);
    si[q] = (int)sf;
    float f = u - sf, gg = 1.0f - f;
    float f2 = f * f, g2 = gg * gg;
    tb0[q] = f2bf(g2 * gg * (1.f / 6.f));
    tb1[q] = f2bf(0.66666667f - f2 + 0.5f * f2 * f);
    tb2[q] = f2bf(0.66666667f - g2 + 0.5f * g2 * gg);
    tb3[q] = f2bf(f2 * f * (1.f / 6.f));
    sgb[q] = f2bf(xn / (1.0f + __expf(-xn)));
  }

#pragma unroll
  for (int wl = 0; wl < 9; ++wl) {
    unsigned short v[32];
#pragma unroll
    for (int kk = 0; kk < 32; ++kk) {
      const int kr = wl * 32 + kk;                // compile-time
      const int q = kr / KPI;                     // compile-time i-index
      const int c = kr % KPI;                     // compile-time coeff
      unsigned short val;
      if (c == NC) {
        val = sgb[q];
      } else {
        int rel = c - (si[q] - 1);
        val = (rel == 0) ? tb0[q]
            : (rel == 1) ? tb1[q]
            : (rel == 2) ? tb2[q]
            : (rel == 3) ? tb3[q] : (unsigned short)0;
      }
      v[kk] = val;
    }
    uint4* dst = (uint4*)(a2 + ((size_t)(w0 + wl) * MROWS + b) * 32);
#pragma unroll
    for (int j = 0; j < 4; ++j) dst[j ^ swz] = pack8(&v[8 * j]);
  }
}

// ---- fast GEMM: R5 geometry (256x256, 8 waves, triple-buffered, vmcnt(4))
// + swizzled ds_read addressing (koS) matching the baked image. ----
__global__ __launch_bounds__(512) void kan_gemm5(const unsigned short* __restrict__ A2,
                                                 const unsigned short* __restrict__ W2,
                                                 float* __restrict__ out) {
  __shared__ __align__(16) unsigned short As[3][BM * BK];   // 3 x 16 KB
  __shared__ __align__(16) unsigned short Ws[3][BN * BK];   // 3 x 16 KB

  const int tid = threadIdx.x;
  const int mt = blockIdx.x, nt = blockIdx.y, kc = blockIdx.z;

  const int lane = tid & 63;
  const int wid = tid >> 6;                      // 0..7
  const int wm = (wid & 3) * 64;                 // 4 m-wave rows
  const int wn = (wid >> 2) * 128;               // 2 n-wave cols
  const int lm = lane & 15;
  const int quad = lane >> 4;
  const int koS = (quad ^ ((lm >> 1) & 3)) * 8;  // swizzled chunk address

  f32x4 acc[4][8];
#pragma unroll
  for (int a = 0; a < 4; ++a)
#pragma unroll
    for (int b = 0; b < 8; ++b) acc[a][b] = f32x4{0.f, 0.f, 0.f, 0.f};

  // staging: wave wid owns 16-row chunks g = 2*wid, 2*wid+1 of both tiles.
  // Each global_load_lds: contiguous 1KB (16 rows x 32 k), lane*16B.
  const unsigned short* Abase = A2 + (size_t)(mt * BM) * 32 + lane * 8;
  const unsigned short* Wbase = W2 + (size_t)(nt * BN) * 32 + lane * 8;

  auto issue = [&](int buf, int w) {
    const size_t aoff = (size_t)w * (MROWS * 32);
    const size_t woff = (size_t)w * (OUT_DIM * 32);
#pragma unroll
    for (int c = 0; c < 2; ++c) {
      const int g = wid * 2 + c;
      __builtin_amdgcn_global_load_lds(
          (const __attribute__((address_space(1))) unsigned int*)(Abase + aoff + (size_t)g * 512),
          (__attribute__((address_space(3))) unsigned int*)(&As[buf][g * 512]),
          16, 0, 0);
      __builtin_amdgcn_global_load_lds(
          (const __attribute__((address_space(1))) unsigned int*)(Wbase + woff + (size_t)g * 512),
          (__attribute__((address_space(3))) unsigned int*)(&Ws[buf][g * 512]),
          16, 0, 0);
    }
  };

  issue(0, kc * WPC);
  int cur = 0, nxt = 1;
  for (int step = 0; step < WPC; ++step) {
    if (step + 1 < WPC) {
      issue(nxt, kc * WPC + step + 1);
      // wait this step's 4 loads only; prefetch (newest 4) stays in flight
      asm volatile("s_waitcnt vmcnt(4) lgkmcnt(0)\ns_barrier" ::: "memory");
    } else {
      asm volatile("s_waitcnt vmcnt(0) lgkmcnt(0)\ns_barrier" ::: "memory");
    }

    uint4 af[4];
#pragma unroll
    for (int mi = 0; mi < 4; ++mi)
      af[mi] = *(const uint4*)(&As[cur][(wm + mi * 16 + lm) * BK + koS]);
#pragma unroll
    for (int h = 0; h < 2; ++h) {
      uint4 bfr[4];
#pragma unroll
      for (int nj = 0; nj < 4; ++nj)
        bfr[nj] = *(const uint4*)(&Ws[cur][(wn + h * 64 + nj * 16 + lm) * BK + koS]);
#pragma unroll
      for (int mi = 0; mi < 4; ++mi)
#pragma unroll
        for (int nj = 0; nj < 4; ++nj)
          acc[mi][h * 4 + nj] = __builtin_amdgcn_mfma_f32_16x16x32_bf16(
              __builtin_bit_cast(bf16x8, af[mi]), __builtin_bit_cast(bf16x8, bfr[nj]),
              acc[mi][h * 4 + nj], 0, 0, 0);
    }

    cur = nxt;
    nxt = (nxt == 2) ? 0 : nxt + 1;
  }

  // epilogue: C/D layout col=lane&15 (n), row=quad*4+reg (m); split-K atomics
#pragma unroll
  for (int mi = 0; mi < 4; ++mi)
#pragma unroll
    for (int ni = 0; ni < 8; ++ni)
#pragma unroll
      for (int r = 0; r < 4; ++r) {
        int row = mt * BM + wm + mi * 16 + quad * 4 + r;
        int col = nt * BN + wn + ni * 16 + lm;
        atomicAdd(&out[(size_t)row * OUT_DIM + col], acc[mi][ni][r]);
      }
}

// ================= fallback path (R1-proven), used only if ws too small ====
#define FB_BM 128
#define FB_BN 128
#define FB_BKPA 40
#define FB_KCH 9216
#define FB_NSTEP 288

__global__ __launch_bounds__(256) void prep_wb_fb(const float* __restrict__ sw,
                                                  const float* __restrict__ bs,
                                                  unsigned short* __restrict__ wb) {
  int id = blockIdx.x * 256 + threadIdx.x;
  int i = id & (IN_DIM - 1);
  int n = id >> 10;
  const float* s = sw + (size_t)i * (OUT_DIM * NC) + (size_t)n * NC;
  unsigned short v[KPI];
#pragma unroll
  for (int c = 0; c < NC; ++c) v[c] = f2bf(s[c]);
  v[NC] = f2bf(bs[(size_t)i * OUT_DIM + n]);
  uint2* dst = (uint2*)(wb + (size_t)n * KTOT + (size_t)i * KPI);
#pragma unroll
  for (int w = 0; w < 9; ++w) {
    uint2 t;
    t.x = (unsigned)v[4 * w + 0] | ((unsigned)v[4 * w + 1] << 16);
    t.y = (unsigned)v[4 * w + 2] | ((unsigned)v[4 * w + 3] << 16);
    dst[w] = t;
  }
}

template <bool USE_WB>
__global__ __launch_bounds__(256) void kan_gemm_fb(const float* __restrict__ x,
                                                   const unsigned short* __restrict__ wb,
                                                   const float* __restrict__ sw,
                                                   const float* __restrict__ bs,
                                                   float* __restrict__ out) {
  __shared__ __align__(16) unsigned short As[FB_BM * FB_BKPA];
  __shared__ __align__(16) unsigned short Wsm[FB_BN * FB_BKPA];

  const int tid = threadIdx.x;
  const int mt = blockIdx.x, nt = blockIdx.y, kc = blockIdx.z;
  const int sb = tid & 127;
  const int shalf = tid >> 7;
  const int klo = shalf * 16;
  const int wrow = tid >> 1;
  const int whal = tid & 1;
  const int lane = tid & 63;
  const int wid = tid >> 6;
  const int wm = (wid & 1) * 64;
  const int wn = (wid >> 1) * 64;
  const int lm = lane & 15;
  const int quad = lane >> 4;
  const int ko = quad * 8;

  f32x4 acc[4][4];
#pragma unroll
  for (int a = 0; a < 4; ++a)
#pragma unroll
    for (int b = 0; b < 4; ++b) acc[a][b] = f32x4{0.f, 0.f, 0.f, 0.f};

  const float* xrow = x + (size_t)(mt * FB_BM + sb) * IN_DIM;

  for (int step = 0; step < FB_NSTEP; ++step) {
    const int kbase = kc * FB_KCH + step * BK;
    {
      uint4 z = make_uint4(0, 0, 0, 0);
      uint4* az = (uint4*)(&As[sb * FB_BKPA + klo]);
      az[0] = z;
      az[1] = z;
    }
    {
      const int ilo = kbase / KPI;
      const int ihi = (kbase + BK - 1) / KPI;
      for (int ii = ilo; ii <= ihi; ++ii) {
        float xv = xrow[ii];
        float xn = fminf(fmaxf(xv, -0.99f), 0.99f);
        float u = (xn + 1.0f) * 17.0f;
        float sf = floorf(u);
        int s = (int)sf;
        float f = u - sf, g = 1.0f - f;
        float f2 = f * f, g2 = g * g;
        float v0 = g2 * g * (1.f / 6.f);
        float v1 = 0.66666667f - f2 + 0.5f * f2 * f;
        float v2 = 0.66666667f - g2 + 0.5f * g2 * g;
        float v3 = f2 * f * (1.f / 6.f);
        float sig = xn / (1.0f + __expf(-xn));
        const int kb0 = ii * KPI - kbase;
#pragma unroll
        for (int t = 0; t < 4; ++t) {
          int c = s - 1 + t;
          float v = (t == 0) ? v0 : (t == 1) ? v1 : (t == 2) ? v2 : v3;
          int kq = kb0 + c;
          if (c >= 0 && c < NC && kq >= klo && kq < klo + 16)
            As[sb * FB_BKPA + kq] = f2bf(v);
        }
        int kqb = kb0 + NC;
        if (kqb >= klo && kqb < klo + 16) As[sb * FB_BKPA + kqb] = f2bf(sig);
      }
    }
    if (USE_WB) {
      const unsigned short* src = wb + (size_t)(nt * FB_BN + wrow) * KTOT + kbase + whal * 16;
      uint4 w0 = ((const uint4*)src)[0];
      uint4 w1 = ((const uint4*)src)[1];
      uint4* wd = (uint4*)(&Wsm[wrow * FB_BKPA + whal * 16]);
      wd[0] = w0;
      wd[1] = w1;
    } else {
      const int j = nt * FB_BN + wrow;
      unsigned int p[8];
#pragma unroll
      for (int q = 0; q < 8; ++q) {
        unsigned int lohi = 0;
#pragma unroll
        for (int h = 0; h < 2; ++h) {
          int k = kbase + whal * 16 + q * 2 + h;
          int i = k / KPI;
          int c = k - i * KPI;
          float v = (c < NC) ? sw[(size_t)i * (OUT_DIM * NC) + (size_t)j * NC + c]
                             : bs[(size_t)i * OUT_DIM + j];
          lohi |= ((unsigned int)f2bf(v)) << (16 * h);
        }
        p[q] = lohi;
      }
      uint4* wd = (uint4*)(&Wsm[wrow * FB_BKPA + whal * 16]);
      wd[0] = make_uint4(p[0], p[1], p[2], p[3]);
      wd[1] = make_uint4(p[4], p[5], p[6], p[7]);
    }

    __syncthreads();

    uint4 af[4], bfr[4];
#pragma unroll
    for (int mi = 0; mi < 4; ++mi)
      af[mi] = *(const uint4*)(&As[(wm + mi * 16 + lm) * FB_BKPA + ko]);
#pragma unroll
    for (int ni = 0; ni < 4; ++ni)
      bfr[ni] = *(const uint4*)(&Wsm[(wn + ni * 16 + lm) * FB_BKPA + ko]);
#pragma unroll
    for (int mi = 0; mi < 4; ++mi)
#pragma unroll
      for (int ni = 0; ni < 4; ++ni)
        acc[mi][ni] = __builtin_amdgcn_mfma_f32_16x16x32_bf16(
            __builtin_bit_cast(bf16x8, af[mi]), __builtin_bit_cast(bf16x8, bfr[ni]),
            acc[mi][ni], 0, 0, 0);

    __syncthreads();
  }

#pragma unroll
  for (int mi = 0; mi < 4; ++mi)
#pragma unroll
    for (int ni = 0; ni < 4; ++ni)
#pragma unroll
      for (int r = 0; r < 4; ++r) {
        int row = mt * FB_BM + wm + mi * 16 + quad * 4 + r;
        int col = nt * FB_BN + wn + ni * 16 + lm;
        atomicAdd(&out[(size_t)row * OUT_DIM + col], acc[mi][ni][r]);
      }
}

extern "C" void kernel_launch(void* const* d_in, const int* in_sizes, int n_in,
                              void* d_out, int out_size, void* d_ws, size_t ws_size,
                              hipStream_t stream) {
  const float* x = (const float*)d_in[0];
  const float* sw = (const float*)d_in[1];
  const float* bs = (const float*)d_in[2];
  float* out = (float*)d_out;

  hipMemsetAsync(d_out, 0, (size_t)MROWS * OUT_DIM * sizeof(float), stream);

  const size_t WB_BYTES = (size_t)NW * OUT_DIM * 32 * sizeof(unsigned short);  // 75.5 MB
  const size_t A_BYTES = (size_t)NW * MROWS * 32 * sizeof(unsigned short);     // 302 MB

  if (ws_size >= WB_BYTES + A_BYTES) {
    unsigned short* w2 = (unsigned short*)d_ws;
    unsigned short* a2 = (unsigned short*)((char*)d_ws + WB_BYTES);
    prep_w2<<<dim3(NW, OUT_DIM / 256), 256, 0, stream>>>(sw, bs, w2);
    prep_a2t<<<dim3(KTOT / 288, MROWS / 256), 256, 0, stream>>>(x, a2);
    kan_gemm5<<<dim3(MROWS / BM, OUT_DIM / BN, NSPLIT), 512, 0, stream>>>(a2, w2, out);
  } else if (ws_size >= WB_BYTES) {
    unsigned short* wbp = (unsigned short*)d_ws;
    prep_wb_fb<<<(IN_DIM * OUT_DIM) / 256, 256, 0, stream>>>(sw, bs, wbp);
    kan_gemm_fb<true><<<dim3(32, 8, 4), 256, 0, stream>>>(x, wbp, sw, bs, out);
  } else {
    kan_gemm_fb<false><<<dim3(32, 8, 4), 256, 0, stream>>>(x, nullptr, sw, bs, out);
  }
}